// Round 23
// baseline (243.931 us; speedup 1.0000x reference)
//
#include <hip/hip_runtime.h>
#include <math.h>

#define G   200
#define G2  40000
#define NPT 128
#define MAXB 32
#define MSAMP 8192
#define NSP 17                 // segment-pairs per n (34 segments of 255)
#define DU (20.0f / 8192.0f)

__device__ __forceinline__ float f_min_lon() { return 95.987f; }
__device__ __forceinline__ float f_min_lat() { return 31.3039f; }
__device__ __forceinline__ float f_dlon()    { return (float)((109.4132 - 95.987) / 200.0); }
__device__ __forceinline__ float f_dlat()    { return (float)((42.879 - 31.3039) / 200.0); }
__device__ __forceinline__ float f_rad()     { return 0.017453292519943295f; }

// fast tanh: proven decision-safe R5-R22 (absmax 0.0 every round).
__device__ __forceinline__ float fast_tanh(float x) {
    float xc = fminf(fmaxf(x, -30.0f), 30.0f);
    float e = __builtin_amdgcn_exp2f(xc * 2.8853900817779268f);
    return (e - 1.0f) * __builtin_amdgcn_rcpf(e + 1.0f);
}

// float offsets relative to wsf base
#define W1A_OFF  0
#define B2F_OFF  32
#define W2F_OFF  64
#define W3P_OFF  1088
#define B3_OFF   1344
#define PERN_OFF 1352
#define C_OFF    2376
#define SLAT_OFF 6472
#define CLAT_OFF 6672
#define SDL_OFF  6872          // 25600*2 floats
#define BND_OFF  58072         // MAXB*128 k-major brackets (pad 2e9, setup-filled)
#define WS_TOTAL (BND_OFF + MAXB*128)

// hdr: d_ws[0..1056) = {key u32 @0, done u32 @4, cnt[128] @16, f0[128] @528} —
// zeroed by setup block 0 (no memset dispatch; same-stream ordering).
__global__ void setup_kernel(const float* __restrict__ x,
                             const float* __restrict__ w1, const float* __restrict__ b1,
                             const float* __restrict__ g1, const float* __restrict__ be1,
                             const float* __restrict__ m1, const float* __restrict__ v1,
                             const float* __restrict__ w2, const float* __restrict__ b2,
                             const float* __restrict__ g2, const float* __restrict__ be2,
                             const float* __restrict__ m2, const float* __restrict__ v2,
                             const float* __restrict__ w3, const float* __restrict__ b3,
                             float* __restrict__ wsf, unsigned* __restrict__ hdr,
                             int has_tab, int has_pq)
{
    const int t = threadIdx.x;
    if (blockIdx.x != 0) {
        if (!has_pq) return;
        int idx = (blockIdx.x - 1) * 256 + t;
        if (idx >= 200 * NPT) return;
        int gj = idx >> 7, n = idx & 127;
        float lon1 = (f_min_lon() + f_dlon() * (float)gj) * f_rad();
        float lon2 = x[n * 4 + 0] * f_rad();
        float dl = lon2 - lon1;
        wsf[SDL_OFF + idx * 2 + 0] = sinf(dl);
        wsf[SDL_OFF + idx * 2 + 1] = cosf(dl);
        return;
    }
    if (hdr) {                                   // zero key/done/cnt/f0 header
        if (t < 264) hdr[t] = 0u;
    }
    for (int idx = t; idx < 1024; idx += 256) {
        int j = idx & 31;
        float a2 = g2[j] / sqrtf(v2[j] + 1e-5f);
        wsf[W2F_OFF + idx] = w2[idx] * a2;
    }
    if (t < 32) {
        float a1 = g1[t] / sqrtf(v1[t] + 1e-5f);
        wsf[W1A_OFF + t] = w1[t] * a1;
        float a2 = g2[t] / sqrtf(v2[t] + 1e-5f);
        wsf[B2F_OFF + t] = (b2[t] - m2[t]) * a2 + be2[t];
    }
    {
        int j = t >> 3, c = t & 7;
        wsf[W3P_OFF + t] = (c < 5) ? w3[j * 5 + c] : 0.0f;
    }
    if (t < 8) wsf[B3_OFF + t] = (t < 5) ? b3[t] : 0.0f;
    if (t < NPT) {
        float lon = x[t * 4 + 0], lat = x[t * 4 + 1];
        float tim = x[t * 4 + 2], rid = x[t * 4 + 3];
        float lat2 = lat * f_rad();
        wsf[PERN_OFF + t * 8 + 0] = sinf(lat2);
        wsf[PERN_OFF + t * 8 + 1] = cosf(lat2);
        wsf[PERN_OFF + t * 8 + 2] = lon * f_rad();
        wsf[PERN_OFF + t * 8 + 3] = tim;
        wsf[PERN_OFF + t * 8 + 4] = rid;
        wsf[PERN_OFF + t * 8 + 5] = 0.0f;
        wsf[PERN_OFF + t * 8 + 6] = 0.0f;
        wsf[PERN_OFF + t * 8 + 7] = 0.0f;
    }
    for (int idx = t; idx < NPT * 32; idx += 256) {
        int n = idx >> 5, k = idx & 31;
        float a1 = g1[k] / sqrtf(v1[k] + 1e-5f);
        float tim = x[n * 4 + 2];
        wsf[C_OFF + idx] = ((tim / 100.0f) * w1[32 + k] + b1[k] - m1[k]) * a1 + be1[k];
    }
    if (has_tab && t < 200) {
        float lat1 = (f_min_lat() + f_dlat() * (float)t) * f_rad();
        wsf[SLAT_OFF + t] = sinf(lat1);
        wsf[CLAT_OFF + t] = cosf(lat1);
    }
    // pre-fill k-major bracket table with pad (sampler overwrites real ones)
    for (int idx = t; idx < MAXB * 128; idx += 256)
        wsf[BND_OFF + idx] = 2.0e9f;
}

// Exact MLP class body — op order IDENTICAL to R12-R22 (absmax 0.0).
template<int DUMMY>
__device__ __forceinline__ int mlp_class_body(float u, int n,
                                              const float* __restrict__ wsf)
{
    const float4* W1A4 = (const float4*)(wsf + W1A_OFF);
    const float4* C4   = (const float4*)(wsf + C_OFF + n * 32);
    float h1[32];
#pragma unroll
    for (int q = 0; q < 8; q++) {
        float4 wa = W1A4[q];
        float4 cc = C4[q];
        h1[4 * q + 0] = fast_tanh(fmaf(u, wa.x, cc.x));
        h1[4 * q + 1] = fast_tanh(fmaf(u, wa.y, cc.y));
        h1[4 * q + 2] = fast_tanh(fmaf(u, wa.z, cc.z));
        h1[4 * q + 3] = fast_tanh(fmaf(u, wa.w, cc.w));
    }
    float lg[5];
#pragma unroll
    for (int c = 0; c < 5; c++) lg[c] = wsf[B3_OFF + c];
#pragma unroll 1
    for (int jc = 0; jc < 4; jc++) {
        float acc[8];
        {
            const float4* B2F4 = (const float4*)(wsf + B2F_OFF + jc * 8);
            float4 b0 = B2F4[0], b1v = B2F4[1];
            acc[0] = b0.x;  acc[1] = b0.y;  acc[2] = b0.z;  acc[3] = b0.w;
            acc[4] = b1v.x; acc[5] = b1v.y; acc[6] = b1v.z; acc[7] = b1v.w;
        }
        const float* wbase = wsf + W2F_OFF + jc * 8;
#pragma unroll
        for (int k = 0; k < 32; k++) {
            const float4* W24 = (const float4*)(wbase + k * 32);
            float4 w0 = W24[0], w1v = W24[1];
            float hk = h1[k];
            acc[0] = fmaf(hk, w0.x,  acc[0]);
            acc[1] = fmaf(hk, w0.y,  acc[1]);
            acc[2] = fmaf(hk, w0.z,  acc[2]);
            acc[3] = fmaf(hk, w0.w,  acc[3]);
            acc[4] = fmaf(hk, w1v.x, acc[4]);
            acc[5] = fmaf(hk, w1v.y, acc[5]);
            acc[6] = fmaf(hk, w1v.z, acc[6]);
            acc[7] = fmaf(hk, w1v.w, acc[7]);
        }
#pragma unroll
        for (int m = 0; m < 8; m++) {
            int j = jc * 8 + m;
            float h2 = fast_tanh(acc[m]);
            const float4* W3P4 = (const float4*)(wsf + W3P_OFF + j * 8);
            float4 wa = W3P4[0];
            float  w4 = wsf[W3P_OFF + j * 8 + 4];
            lg[0] = fmaf(h2, wa.x, lg[0]);
            lg[1] = fmaf(h2, wa.y, lg[1]);
            lg[2] = fmaf(h2, wa.z, lg[2]);
            lg[3] = fmaf(h2, wa.w, lg[3]);
            lg[4] = fmaf(h2, w4,   lg[4]);
        }
    }
    int best = 0;
    float bv = lg[0];
#pragma unroll
    for (int c = 1; c < 5; c++)
        if (lg[c] > bv) { bv = lg[c]; best = c; }
    return best;
}

// Compact noinline copy: count's rare exact evals AND the fused finalize.
__device__ __noinline__ int mlp_class(float u, int n, const float* __restrict__ wsf)
{
    return mlp_class_body<0>(u, n, wsf);
}
__device__ __forceinline__ int mlp_class_inl(float u, int n, const float* __restrict__ wsf)
{
    return mlp_class_body<1>(u, n, wsf);
}

__device__ __forceinline__ int mlp_match(float u, int n, const float* __restrict__ wsf,
                                         float rid)
{
    return ((float)mlp_class(u, n, wsf) == rid) ? 1 : 0;
}

// Two interleaved evals — 2-chain ILP, R12/R17-proven (sampler hot path).
__device__ void mlp_class2(float u0, float u1, int n, const float* __restrict__ wsf,
                           int& p0, int& p1)
{
    const float4* W1A4 = (const float4*)(wsf + W1A_OFF);
    const float4* C4   = (const float4*)(wsf + C_OFF + n * 32);
    float h1a[32], h1b[32];
#pragma unroll
    for (int q = 0; q < 8; q++) {
        float4 wa = W1A4[q];
        float4 cc = C4[q];
        h1a[4 * q + 0] = fast_tanh(fmaf(u0, wa.x, cc.x));
        h1b[4 * q + 0] = fast_tanh(fmaf(u1, wa.x, cc.x));
        h1a[4 * q + 1] = fast_tanh(fmaf(u0, wa.y, cc.y));
        h1b[4 * q + 1] = fast_tanh(fmaf(u1, wa.y, cc.y));
        h1a[4 * q + 2] = fast_tanh(fmaf(u0, wa.z, cc.z));
        h1b[4 * q + 2] = fast_tanh(fmaf(u1, wa.z, cc.z));
        h1a[4 * q + 3] = fast_tanh(fmaf(u0, wa.w, cc.w));
        h1b[4 * q + 3] = fast_tanh(fmaf(u1, wa.w, cc.w));
    }
    float lga[5], lgb[5];
#pragma unroll
    for (int c = 0; c < 5; c++) { lga[c] = wsf[B3_OFF + c]; lgb[c] = wsf[B3_OFF + c]; }
#pragma unroll 1
    for (int jc = 0; jc < 4; jc++) {
        float aa[8], ab[8];
        {
            const float4* B2F4 = (const float4*)(wsf + B2F_OFF + jc * 8);
            float4 b0 = B2F4[0], b1v = B2F4[1];
            aa[0] = b0.x;  aa[1] = b0.y;  aa[2] = b0.z;  aa[3] = b0.w;
            aa[4] = b1v.x; aa[5] = b1v.y; aa[6] = b1v.z; aa[7] = b1v.w;
            ab[0] = b0.x;  ab[1] = b0.y;  ab[2] = b0.z;  ab[3] = b0.w;
            ab[4] = b1v.x; ab[5] = b1v.y; ab[6] = b1v.z; ab[7] = b1v.w;
        }
        const float* wbase = wsf + W2F_OFF + jc * 8;
#pragma unroll
        for (int k = 0; k < 32; k++) {
            const float4* W24 = (const float4*)(wbase + k * 32);
            float4 w0 = W24[0], w1v = W24[1];
            float hka = h1a[k], hkb = h1b[k];
            aa[0] = fmaf(hka, w0.x,  aa[0]);  ab[0] = fmaf(hkb, w0.x,  ab[0]);
            aa[1] = fmaf(hka, w0.y,  aa[1]);  ab[1] = fmaf(hkb, w0.y,  ab[1]);
            aa[2] = fmaf(hka, w0.z,  aa[2]);  ab[2] = fmaf(hkb, w0.z,  ab[2]);
            aa[3] = fmaf(hka, w0.w,  aa[3]);  ab[3] = fmaf(hkb, w0.w,  ab[3]);
            aa[4] = fmaf(hka, w1v.x, aa[4]);  ab[4] = fmaf(hkb, w1v.x, ab[4]);
            aa[5] = fmaf(hka, w1v.y, aa[5]);  ab[5] = fmaf(hkb, w1v.y, ab[5]);
            aa[6] = fmaf(hka, w1v.z, aa[6]);  ab[6] = fmaf(hkb, w1v.z, ab[6]);
            aa[7] = fmaf(hka, w1v.w, aa[7]);  ab[7] = fmaf(hkb, w1v.w, ab[7]);
        }
#pragma unroll
        for (int m = 0; m < 8; m++) {
            int j = jc * 8 + m;
            const float4* W3P4 = (const float4*)(wsf + W3P_OFF + j * 8);
            float4 wa = W3P4[0];
            float  w4 = wsf[W3P_OFF + j * 8 + 4];
            float h2a = fast_tanh(aa[m]);
            float h2b = fast_tanh(ab[m]);
            lga[0] = fmaf(h2a, wa.x, lga[0]);  lgb[0] = fmaf(h2b, wa.x, lgb[0]);
            lga[1] = fmaf(h2a, wa.y, lga[1]);  lgb[1] = fmaf(h2b, wa.y, lgb[1]);
            lga[2] = fmaf(h2a, wa.z, lga[2]);  lgb[2] = fmaf(h2b, wa.z, lgb[2]);
            lga[3] = fmaf(h2a, wa.w, lga[3]);  lgb[3] = fmaf(h2b, wa.w, lgb[3]);
            lga[4] = fmaf(h2a, w4,   lga[4]);  lgb[4] = fmaf(h2b, w4,   lgb[4]);
        }
    }
    int ba = 0; float va = lga[0];
    int bb = 0; float vb = lgb[0];
#pragma unroll
    for (int c = 1; c < 5; c++) {
        if (lga[c] > va) { va = lga[c]; ba = c; }
        if (lgb[c] > vb) { vb = lgb[c]; bb = c; }
    }
    p0 = ba; p1 = bb;
}

// Dense sampler, 2 evals/thread; brackets written k-major into BND.
__global__ __launch_bounds__(256, 2) void sample_kernel(float* __restrict__ wsf,
                                                        int* __restrict__ cnt,
                                                        int* __restrict__ f0arr)
{
    __shared__ unsigned char smA[256], smB[256];
    const int b = blockIdx.x;                 // 0 .. 128*NSP-1
    const int n = b / NSP, sp = b - n * NSP;
    const int segA = 2 * sp, segB = 2 * sp + 1;
    const int t = threadIdx.x;
    const float rid = wsf[PERN_OFF + n * 8 + 4];

    int sA = segA * 255 + t; if (sA > MSAMP - 1) sA = MSAMP - 1;
    int sB = segB * 255 + t; if (sB > MSAMP - 1) sB = MSAMP - 1;
    int pA, pB;
    mlp_class2((float)sA * DU, (float)sB * DU, n, wsf, pA, pB);
    int mA = ((float)pA == rid) ? 1 : 0;
    int mB = ((float)pB == rid) ? 1 : 0;
    smA[t] = (unsigned char)mA;
    smB[t] = (unsigned char)mB;
    if (sp == 0 && t == 0) f0arr[n] = mA;
    __syncthreads();
    if (t < 255) {
        int s2 = segA * 255 + t;
        if (s2 + 1 <= MSAMP - 1 && smA[t] != smA[t + 1]) {
            int idx = atomicAdd(&cnt[n], 1);
            if (idx < MAXB) wsf[BND_OFF + idx * 128 + n] = (float)s2;
        }
        int s3 = segB * 255 + t;
        if (s3 + 1 <= MSAMP - 1 && smB[t] != smB[t + 1]) {
            int idx = atomicAdd(&cnt[n], 1);
            if (idx < MAXB) wsf[BND_OFF + idx * 128 + n] = (float)s3;
        }
    }
}

// Count pass + fused last-block finalize. 2500 blocks x 16 points.
// Software-pipelined loop (prefetch it+1's SLAT/CLAT/SDL loads — same
// addresses, bit-identical values). Finalize: ONLY t==0 fences (R11 lesson:
// all-thread fences collapsed the chip; 2500 single-lane fences are cheap),
// last block recomputes winner row with the compact noinline eval (R18
// lesson: keep hot-loop I-footprint small).
__global__ __launch_bounds__(256, 2) void count_kernel(const float* __restrict__ wsf,
                                                       const int* __restrict__ f0arr,
                                                       unsigned* __restrict__ key,
                                                       unsigned* __restrict__ done,
                                                       float* __restrict__ out)
{
    __shared__ int scnt[4][8];
    __shared__ unsigned skey[16];
    __shared__ unsigned s_key;
    __shared__ int s_last;
    const int t = threadIdx.x;
    const int n = t & 127;
    const int h = t >> 7;
    const int w = t >> 6;

    float bs[MAXB];
#pragma unroll
    for (int k = 0; k < MAXB; k++) bs[k] = wsf[BND_OFF + k * 128 + n];
    const int f0 = f0arr[n];
    const float rid = wsf[PERN_OFF + n * 8 + 4];
    const float* pn = wsf + PERN_OFF + n * 8;
    const float slat2 = pn[0], clat2 = pn[1];
    const int base = blockIdx.x * 16 + h * 8;

    // prefetch iteration 0
    int i0 = base;
    int gi0 = i0 / G, gj0 = i0 - gi0 * G;
    float s1n = wsf[SLAT_OFF + gi0], c1n = wsf[CLAT_OFF + gi0];
    float2 tvn = ((const float2*)(wsf + SDL_OFF))[gj0 * NPT + n];

#pragma unroll 1
    for (int it = 0; it < 8; ++it) {
        float s1 = s1n, c1 = c1n;
        float2 tv = tvn;
        if (it < 7) {                        // prefetch it+1 (overlaps body)
            int i1 = base + it + 1;
            int gi1 = i1 / G, gj1 = i1 - gi1 * G;
            s1n = wsf[SLAT_OFF + gi1];
            c1n = wsf[CLAT_OFF + gi1];
            tvn = ((const float2*)(wsf + SDL_OFF))[gj1 * NPT + n];
        }
        float sdl = tv.x, cdl = tv.y;
        float A = clat2 * sdl;
        float B = c1 * slat2 - s1 * clat2 * cdl;
        float numer = sqrtf(A * A + B * B);
        float denom = s1 * slat2 + c1 * clat2 * cdl;
        float u = (atan2f(numer, denom) * 6371.0f) / 100.0f;
        int c = 0, inside = 0;
#pragma unroll
        for (int k = 0; k < MAXB; k++) {
            float sk = bs[k];
            float lo = sk * DU;
            float hi = (sk + 1.0f) * DU;     // same exprs as sampler -> bit-identical
            c += (hi <= u) ? 1 : 0;
            inside |= (lo < u && u < hi) ? 1 : 0;
        }
        int m = f0 ^ (c & 1);
        if (inside) m = mlp_match(u, n, wsf, rid);   // exact, rare (noinline)
        unsigned long long bal = __ballot(m != 0);
        if ((t & 63) == 0) scnt[w][it] = __popcll(bal);
    }
    __syncthreads();
    if (t < 16) {
        int hh = t >> 3, j = t & 7;
        int i = blockIdx.x * 16 + hh * 8 + j;
        int num = scnt[hh * 2][j] + scnt[hh * 2 + 1][j];
        skey[t] = ((unsigned)num << 16) | (unsigned)(G2 - 1 - i);
    }
    __syncthreads();
    if (t == 0) {
        unsigned km = 0;
        for (int q = 0; q < 16; q++) km = max(km, skey[q]);
        atomicMax(key, km);
        __threadfence();                     // t0-only: order max before done++
        unsigned old = atomicAdd(done, 1u);
        s_last = (old == (unsigned)(gridDim.x - 1));
        if (s_last) s_key = atomicAdd(key, 0u);
    }
    __syncthreads();
    if (!s_last) return;

    // ---- last-block finalize (replaces final_kernel dispatch) ----
    unsigned kf = s_key;
    int iwin = (G2 - 1) - (int)(kf & 0xFFFFu);
    int numw = (int)(kf >> 16);
    if (t < NPT) {
        int gi = iwin / G, gj = iwin - gi * G;
        float s1 = wsf[SLAT_OFF + gi], c1 = wsf[CLAT_OFF + gi];
        float2 tv = ((const float2*)(wsf + SDL_OFF))[gj * NPT + t];
        const float* pt = wsf + PERN_OFF + t * 8;
        float sl2 = pt[0], cl2 = pt[1];
        float A = cl2 * tv.x;
        float B = c1 * sl2 - s1 * cl2 * tv.y;
        float numer = sqrtf(A * A + B * B);
        float denom = s1 * sl2 + c1 * cl2 * tv.y;
        float gd = atan2f(numer, denom) * 6371.0f;
        int pid = mlp_class(gd / 100.0f, t, wsf);
        out[t] = (float)pid;
        float tim = pt[3];
        out[NPT + 2 * t + 0] = (gd / 100.0f) * 100.0f;
        out[NPT + 2 * t + 1] = (tim / 100.0f) * 100.0f;
        if (t == 0) {
            out[3 * NPT] = (float)numw;
            out[3 * NPT + 1] = f_min_lon() + f_dlon() * (float)gj;
            out[3 * NPT + 2] = f_min_lat() + f_dlat() * (float)gi;
        }
    }
}

// ================= R12 fallback path (ws too small) =================
template<bool TAB, bool PQ>
__device__ __forceinline__ void compute_pair2(int ia, int n,
                                              const float* __restrict__ wsf,
                                              int& pa, int& pb)
{
    const int ib = ia + 1;
    int gia = ia / G, gja = ia - gia * G;
    int gib = ib / G, gjb = ib - gib * G;
    float s1a, c1a, s1b, c1b;
    if (TAB) {
        s1a = wsf[SLAT_OFF + gia]; c1a = wsf[CLAT_OFF + gia];
        s1b = wsf[SLAT_OFF + gib]; c1b = wsf[CLAT_OFF + gib];
    } else {
        float lat1a = (f_min_lat() + f_dlat() * (float)gia) * f_rad();
        float lat1b = (f_min_lat() + f_dlat() * (float)gib) * f_rad();
        s1a = sinf(lat1a); c1a = cosf(lat1a);
        s1b = sinf(lat1b); c1b = cosf(lat1b);
    }
    const float* pn = wsf + PERN_OFF + n * 8;
    float slat2 = pn[0], clat2 = pn[1];
    float sdla, cdla, sdlb, cdlb;
    if (PQ) {
        const float2* T = (const float2*)(wsf + SDL_OFF);
        float2 ta = T[gja * NPT + n];
        float2 tb = T[gjb * NPT + n];
        sdla = ta.x; cdla = ta.y; sdlb = tb.x; cdlb = tb.y;
    } else {
        float lon2 = pn[2];
        float lon1a = (f_min_lon() + f_dlon() * (float)gja) * f_rad();
        float lon1b = (f_min_lon() + f_dlon() * (float)gjb) * f_rad();
        float dla = lon2 - lon1a, dlb = lon2 - lon1b;
        sdla = sinf(dla); cdla = cosf(dla);
        sdlb = sinf(dlb); cdlb = cosf(dlb);
    }
    float Aa = clat2 * sdla;
    float Ba = c1a * slat2 - s1a * clat2 * cdla;
    float Ab = clat2 * sdlb;
    float Bb = c1b * slat2 - s1b * clat2 * cdlb;
    float na_ = sqrtf(Aa * Aa + Ba * Ba);
    float nb_ = sqrtf(Ab * Ab + Bb * Bb);
    float da_ = s1a * slat2 + c1a * clat2 * cdla;
    float db_ = s1b * slat2 + c1b * clat2 * cdlb;
    float ua = (atan2f(na_, da_) * 6371.0f) / 100.0f;
    float ub = (atan2f(nb_, db_) * 6371.0f) / 100.0f;
    int pa_, pb_;
    mlp_class2(ua, ub, n, wsf, pa_, pb_);
    pa = pa_; pb = pb_;
}

template<bool TAB, bool PQ>
__global__ __launch_bounds__(256, 2) void fb_pass1(const float* __restrict__ wsf,
                                                   unsigned* __restrict__ key)
{
    __shared__ int sa[4], sb[4];
    const int t = threadIdx.x;
    const int n = t & 127;
    const int h = t >> 7;
    const int base = blockIdx.x * 4;
    const int ia = base + h * 2;
    int pa, pb;
    compute_pair2<TAB, PQ>(ia, n, wsf, pa, pb);
    float rid = wsf[PERN_OFF + n * 8 + 4];
    unsigned long long ba_ = __ballot((float)pa == rid);
    unsigned long long bb_ = __ballot((float)pb == rid);
    if ((t & 63) == 0) { sa[t >> 6] = __popcll(ba_); sb[t >> 6] = __popcll(bb_); }
    __syncthreads();
    if (t == 0) {
        int n0 = sa[0] + sa[1], n1 = sb[0] + sb[1];
        int n2 = sa[2] + sa[3], n3 = sb[2] + sb[3];
        unsigned k0 = ((unsigned)n0 << 16) | (unsigned)(G2 - 1 - (base + 0));
        unsigned k1 = ((unsigned)n1 << 16) | (unsigned)(G2 - 1 - (base + 1));
        unsigned k2 = ((unsigned)n2 << 16) | (unsigned)(G2 - 1 - (base + 2));
        unsigned k3 = ((unsigned)n3 << 16) | (unsigned)(G2 - 1 - (base + 3));
        atomicMax(key, max(max(k0, k1), max(k2, k3)));
    }
}

template<bool TAB, bool PQ>
__global__ __launch_bounds__(NPT) void fb_pass2(const float* __restrict__ wsf,
                                                const unsigned* __restrict__ key,
                                                float* __restrict__ out)
{
    unsigned k = *key;
    int i = (G2 - 1) - (int)(k & 0xFFFFu);
    int num = (int)(k >> 16);
    const int n = threadIdx.x;
    int gi = i / G, gj = i - gi * G;
    float s1, c1;
    if (TAB) { s1 = wsf[SLAT_OFF + gi]; c1 = wsf[CLAT_OFF + gi]; }
    else {
        float lat1 = (f_min_lat() + f_dlat() * (float)gi) * f_rad();
        s1 = sinf(lat1); c1 = cosf(lat1);
    }
    const float* pn = wsf + PERN_OFF + n * 8;
    float slat2 = pn[0], clat2 = pn[1];
    float sdl, cdl;
    if (PQ) {
        float2 tv = ((const float2*)(wsf + SDL_OFF))[gj * NPT + n];
        sdl = tv.x; cdl = tv.y;
    } else {
        float lon2 = pn[2];
        float lon1 = (f_min_lon() + f_dlon() * (float)gj) * f_rad();
        float dl = lon2 - lon1;
        sdl = sinf(dl); cdl = cosf(dl);
    }
    float A = clat2 * sdl;
    float B = c1 * slat2 - s1 * clat2 * cdl;
    float numer = sqrtf(A * A + B * B);
    float denom = s1 * slat2 + c1 * clat2 * cdl;
    float gd = atan2f(numer, denom) * 6371.0f;
    int pid = mlp_class_inl(gd / 100.0f, n, wsf);
    out[n] = (float)pid;
    float tim = pn[3];
    out[NPT + 2 * n + 0] = (gd / 100.0f) * 100.0f;
    out[NPT + 2 * n + 1] = (tim / 100.0f) * 100.0f;
    if (n == 0) {
        out[3 * NPT] = (float)num;
        out[3 * NPT + 1] = f_min_lon() + f_dlon() * (float)gj;
        out[3 * NPT + 2] = f_min_lat() + f_dlat() * (float)gi;
    }
}

extern "C" void kernel_launch(void* const* d_in, const int* in_sizes, int n_in,
                              void* d_out, int out_size, void* d_ws, size_t ws_size,
                              hipStream_t stream)
{
    const float* x   = (const float*)d_in[0];
    const float* w1  = (const float*)d_in[1];
    const float* b1  = (const float*)d_in[2];
    const float* g1  = (const float*)d_in[3];
    const float* be1 = (const float*)d_in[4];
    const float* m1  = (const float*)d_in[5];
    const float* v1  = (const float*)d_in[6];
    const float* w2  = (const float*)d_in[7];
    const float* b2  = (const float*)d_in[8];
    const float* g2  = (const float*)d_in[9];
    const float* be2 = (const float*)d_in[10];
    const float* m2  = (const float*)d_in[11];
    const float* v2  = (const float*)d_in[12];
    const float* w3  = (const float*)d_in[13];
    const float* b3  = (const float*)d_in[14];
    float* out = (float*)d_out;

    const size_t need_full = 1056 + 4ull * WS_TOTAL;
    if (ws_size >= need_full) {
        unsigned* hdr  = (unsigned*)d_ws;
        unsigned* key  = (unsigned*)d_ws;
        unsigned* done = (unsigned*)((char*)d_ws + 4);
        int* cnt = (int*)((char*)d_ws + 16);
        int* f0  = (int*)((char*)d_ws + 528);
        float* wsf = (float*)((char*)d_ws + 1056);
        setup_kernel<<<101, 256, 0, stream>>>(x, w1, b1, g1, be1, m1, v1,
                                              w2, b2, g2, be2, m2, v2, w3, b3,
                                              wsf, hdr, 1, 1);
        sample_kernel<<<128 * NSP, 256, 0, stream>>>(wsf, cnt, f0);
        count_kernel<<<G2 / 16, 256, 0, stream>>>(wsf, f0, key, done, out);
        return;
    }

    // fallback: R12 path (wsf at d_ws+16)
    unsigned* key = (unsigned*)d_ws;
    float* wsf = (float*)((char*)d_ws + 16);
    const size_t need_tab = 16 + 4ull * (CLAT_OFF + 200);
    const size_t need_pq  = 16 + 4ull * (SDL_OFF + 200 * 128 * 2);
    const bool tab = ws_size >= need_tab;
    const bool pq  = ws_size >= need_pq;
    hipMemsetAsync(d_ws, 0, 16, stream);
    setup_kernel<<<pq ? 101 : 1, 256, 0, stream>>>(x, w1, b1, g1, be1, m1, v1,
                                                   w2, b2, g2, be2, m2, v2, w3, b3, wsf,
                                                   (unsigned*)nullptr,
                                                   tab ? 1 : 0, pq ? 1 : 0);
    if (pq) {
        fb_pass1<true, true><<<G2 / 4, 256, 0, stream>>>(wsf, key);
        fb_pass2<true, true><<<1, NPT, 0, stream>>>(wsf, key, out);
    } else if (tab) {
        fb_pass1<true, false><<<G2 / 4, 256, 0, stream>>>(wsf, key);
        fb_pass2<true, false><<<1, NPT, 0, stream>>>(wsf, key, out);
    } else {
        fb_pass1<false, false><<<G2 / 4, 256, 0, stream>>>(wsf, key);
        fb_pass2<false, false><<<1, NPT, 0, stream>>>(wsf, key, out);
    }
}

// Round 24
// 206.347 us; speedup vs baseline: 1.1821x; 1.1821x over previous
//
#include <hip/hip_runtime.h>
#include <math.h>

#define G   200
#define G2  40000
#define NPT 128
#define MAXB 32
#define MSAMP 8192
#define NSP 17                 // segment-pairs per n (34 segments of 255)
#define DU (20.0f / 8192.0f)

__device__ __forceinline__ float f_min_lon() { return 95.987f; }
__device__ __forceinline__ float f_min_lat() { return 31.3039f; }
__device__ __forceinline__ float f_dlon()    { return (float)((109.4132 - 95.987) / 200.0); }
__device__ __forceinline__ float f_dlat()    { return (float)((42.879 - 31.3039) / 200.0); }
__device__ __forceinline__ float f_rad()     { return 0.017453292519943295f; }

// fast tanh: proven decision-safe R5-R23 (absmax 0.0 every round).
__device__ __forceinline__ float fast_tanh(float x) {
    float xc = fminf(fmaxf(x, -30.0f), 30.0f);
    float e = __builtin_amdgcn_exp2f(xc * 2.8853900817779268f);
    return (e - 1.0f) * __builtin_amdgcn_rcpf(e + 1.0f);
}

// float offsets relative to wsf base
#define W1A_OFF  0
#define B2F_OFF  32
#define W2F_OFF  64
#define W3P_OFF  1088
#define B3_OFF   1344
#define PERN_OFF 1352
#define C_OFF    2376
#define SLAT_OFF 6472
#define CLAT_OFF 6672
#define SDL_OFF  6872          // 25600*2 floats
#define BND_OFF  58072         // MAXB*128 k-major brackets (pad 2e9, setup-filled)
#define WS_TOTAL (BND_OFF + MAXB*128)

// hdr: d_ws[0..1056) = {key u32, pad, cnt[128] @16, f0[128] @528} — zeroed by
// setup block 0 (no memset dispatch; same-stream ordering).
__global__ void setup_kernel(const float* __restrict__ x,
                             const float* __restrict__ w1, const float* __restrict__ b1,
                             const float* __restrict__ g1, const float* __restrict__ be1,
                             const float* __restrict__ m1, const float* __restrict__ v1,
                             const float* __restrict__ w2, const float* __restrict__ b2,
                             const float* __restrict__ g2, const float* __restrict__ be2,
                             const float* __restrict__ m2, const float* __restrict__ v2,
                             const float* __restrict__ w3, const float* __restrict__ b3,
                             float* __restrict__ wsf, unsigned* __restrict__ hdr,
                             int has_tab, int has_pq)
{
    const int t = threadIdx.x;
    if (blockIdx.x != 0) {
        if (!has_pq) return;
        int idx = (blockIdx.x - 1) * 256 + t;
        if (idx >= 200 * NPT) return;
        int gj = idx >> 7, n = idx & 127;
        float lon1 = (f_min_lon() + f_dlon() * (float)gj) * f_rad();
        float lon2 = x[n * 4 + 0] * f_rad();
        float dl = lon2 - lon1;
        wsf[SDL_OFF + idx * 2 + 0] = sinf(dl);
        wsf[SDL_OFF + idx * 2 + 1] = cosf(dl);
        return;
    }
    if (hdr) {                                   // zero key/cnt/f0 header
        if (t < 264) hdr[t] = 0u;
    }
    for (int idx = t; idx < 1024; idx += 256) {
        int j = idx & 31;
        float a2 = g2[j] / sqrtf(v2[j] + 1e-5f);
        wsf[W2F_OFF + idx] = w2[idx] * a2;
    }
    if (t < 32) {
        float a1 = g1[t] / sqrtf(v1[t] + 1e-5f);
        wsf[W1A_OFF + t] = w1[t] * a1;
        float a2 = g2[t] / sqrtf(v2[t] + 1e-5f);
        wsf[B2F_OFF + t] = (b2[t] - m2[t]) * a2 + be2[t];
    }
    {
        int j = t >> 3, c = t & 7;
        wsf[W3P_OFF + t] = (c < 5) ? w3[j * 5 + c] : 0.0f;
    }
    if (t < 8) wsf[B3_OFF + t] = (t < 5) ? b3[t] : 0.0f;
    if (t < NPT) {
        float lon = x[t * 4 + 0], lat = x[t * 4 + 1];
        float tim = x[t * 4 + 2], rid = x[t * 4 + 3];
        float lat2 = lat * f_rad();
        wsf[PERN_OFF + t * 8 + 0] = sinf(lat2);
        wsf[PERN_OFF + t * 8 + 1] = cosf(lat2);
        wsf[PERN_OFF + t * 8 + 2] = lon * f_rad();
        wsf[PERN_OFF + t * 8 + 3] = tim;
        wsf[PERN_OFF + t * 8 + 4] = rid;
        wsf[PERN_OFF + t * 8 + 5] = 0.0f;
        wsf[PERN_OFF + t * 8 + 6] = 0.0f;
        wsf[PERN_OFF + t * 8 + 7] = 0.0f;
    }
    for (int idx = t; idx < NPT * 32; idx += 256) {
        int n = idx >> 5, k = idx & 31;
        float a1 = g1[k] / sqrtf(v1[k] + 1e-5f);
        float tim = x[n * 4 + 2];
        wsf[C_OFF + idx] = ((tim / 100.0f) * w1[32 + k] + b1[k] - m1[k]) * a1 + be1[k];
    }
    if (has_tab && t < 200) {
        float lat1 = (f_min_lat() + f_dlat() * (float)t) * f_rad();
        wsf[SLAT_OFF + t] = sinf(lat1);
        wsf[CLAT_OFF + t] = cosf(lat1);
    }
    // pre-fill k-major bracket table with pad (sampler overwrites real ones)
    for (int idx = t; idx < MAXB * 128; idx += 256)
        wsf[BND_OFF + idx] = 2.0e9f;
}

// Exact MLP class body — op order IDENTICAL to R12-R23 (absmax 0.0).
template<int DUMMY>
__device__ __forceinline__ int mlp_class_body(float u, int n,
                                              const float* __restrict__ wsf)
{
    const float4* W1A4 = (const float4*)(wsf + W1A_OFF);
    const float4* C4   = (const float4*)(wsf + C_OFF + n * 32);
    float h1[32];
#pragma unroll
    for (int q = 0; q < 8; q++) {
        float4 wa = W1A4[q];
        float4 cc = C4[q];
        h1[4 * q + 0] = fast_tanh(fmaf(u, wa.x, cc.x));
        h1[4 * q + 1] = fast_tanh(fmaf(u, wa.y, cc.y));
        h1[4 * q + 2] = fast_tanh(fmaf(u, wa.z, cc.z));
        h1[4 * q + 3] = fast_tanh(fmaf(u, wa.w, cc.w));
    }
    float lg[5];
#pragma unroll
    for (int c = 0; c < 5; c++) lg[c] = wsf[B3_OFF + c];
#pragma unroll 1
    for (int jc = 0; jc < 4; jc++) {
        float acc[8];
        {
            const float4* B2F4 = (const float4*)(wsf + B2F_OFF + jc * 8);
            float4 b0 = B2F4[0], b1v = B2F4[1];
            acc[0] = b0.x;  acc[1] = b0.y;  acc[2] = b0.z;  acc[3] = b0.w;
            acc[4] = b1v.x; acc[5] = b1v.y; acc[6] = b1v.z; acc[7] = b1v.w;
        }
        const float* wbase = wsf + W2F_OFF + jc * 8;
#pragma unroll
        for (int k = 0; k < 32; k++) {
            const float4* W24 = (const float4*)(wbase + k * 32);
            float4 w0 = W24[0], w1v = W24[1];
            float hk = h1[k];
            acc[0] = fmaf(hk, w0.x,  acc[0]);
            acc[1] = fmaf(hk, w0.y,  acc[1]);
            acc[2] = fmaf(hk, w0.z,  acc[2]);
            acc[3] = fmaf(hk, w0.w,  acc[3]);
            acc[4] = fmaf(hk, w1v.x, acc[4]);
            acc[5] = fmaf(hk, w1v.y, acc[5]);
            acc[6] = fmaf(hk, w1v.z, acc[6]);
            acc[7] = fmaf(hk, w1v.w, acc[7]);
        }
#pragma unroll
        for (int m = 0; m < 8; m++) {
            int j = jc * 8 + m;
            float h2 = fast_tanh(acc[m]);
            const float4* W3P4 = (const float4*)(wsf + W3P_OFF + j * 8);
            float4 wa = W3P4[0];
            float  w4 = wsf[W3P_OFF + j * 8 + 4];
            lg[0] = fmaf(h2, wa.x, lg[0]);
            lg[1] = fmaf(h2, wa.y, lg[1]);
            lg[2] = fmaf(h2, wa.z, lg[2]);
            lg[3] = fmaf(h2, wa.w, lg[3]);
            lg[4] = fmaf(h2, w4,   lg[4]);
        }
    }
    int best = 0;
    float bv = lg[0];
#pragma unroll
    for (int c = 1; c < 5; c++)
        if (lg[c] > bv) { bv = lg[c]; best = c; }
    return best;
}

// Compact noinline copy for count's rare exec-masked exact evals (R18 lesson).
__device__ __noinline__ int mlp_class(float u, int n, const float* __restrict__ wsf)
{
    return mlp_class_body<0>(u, n, wsf);
}
// Inlined copy for final (lone block; call overhead matters, I-cache doesn't).
__device__ __forceinline__ int mlp_class_inl(float u, int n, const float* __restrict__ wsf)
{
    return mlp_class_body<1>(u, n, wsf);
}

__device__ __forceinline__ int mlp_match(float u, int n, const float* __restrict__ wsf,
                                         float rid)
{
    return ((float)mlp_class(u, n, wsf) == rid) ? 1 : 0;
}

// Two interleaved evals — 2-chain ILP, R12/R17-proven (sampler hot path).
__device__ void mlp_class2(float u0, float u1, int n, const float* __restrict__ wsf,
                           int& p0, int& p1)
{
    const float4* W1A4 = (const float4*)(wsf + W1A_OFF);
    const float4* C4   = (const float4*)(wsf + C_OFF + n * 32);
    float h1a[32], h1b[32];
#pragma unroll
    for (int q = 0; q < 8; q++) {
        float4 wa = W1A4[q];
        float4 cc = C4[q];
        h1a[4 * q + 0] = fast_tanh(fmaf(u0, wa.x, cc.x));
        h1b[4 * q + 0] = fast_tanh(fmaf(u1, wa.x, cc.x));
        h1a[4 * q + 1] = fast_tanh(fmaf(u0, wa.y, cc.y));
        h1b[4 * q + 1] = fast_tanh(fmaf(u1, wa.y, cc.y));
        h1a[4 * q + 2] = fast_tanh(fmaf(u0, wa.z, cc.z));
        h1b[4 * q + 2] = fast_tanh(fmaf(u1, wa.z, cc.z));
        h1a[4 * q + 3] = fast_tanh(fmaf(u0, wa.w, cc.w));
        h1b[4 * q + 3] = fast_tanh(fmaf(u1, wa.w, cc.w));
    }
    float lga[5], lgb[5];
#pragma unroll
    for (int c = 0; c < 5; c++) { lga[c] = wsf[B3_OFF + c]; lgb[c] = wsf[B3_OFF + c]; }
#pragma unroll 1
    for (int jc = 0; jc < 4; jc++) {
        float aa[8], ab[8];
        {
            const float4* B2F4 = (const float4*)(wsf + B2F_OFF + jc * 8);
            float4 b0 = B2F4[0], b1v = B2F4[1];
            aa[0] = b0.x;  aa[1] = b0.y;  aa[2] = b0.z;  aa[3] = b0.w;
            aa[4] = b1v.x; aa[5] = b1v.y; aa[6] = b1v.z; aa[7] = b1v.w;
            ab[0] = b0.x;  ab[1] = b0.y;  ab[2] = b0.z;  ab[3] = b0.w;
            ab[4] = b1v.x; ab[5] = b1v.y; ab[6] = b1v.z; ab[7] = b1v.w;
        }
        const float* wbase = wsf + W2F_OFF + jc * 8;
#pragma unroll
        for (int k = 0; k < 32; k++) {
            const float4* W24 = (const float4*)(wbase + k * 32);
            float4 w0 = W24[0], w1v = W24[1];
            float hka = h1a[k], hkb = h1b[k];
            aa[0] = fmaf(hka, w0.x,  aa[0]);  ab[0] = fmaf(hkb, w0.x,  ab[0]);
            aa[1] = fmaf(hka, w0.y,  aa[1]);  ab[1] = fmaf(hkb, w0.y,  ab[1]);
            aa[2] = fmaf(hka, w0.z,  aa[2]);  ab[2] = fmaf(hkb, w0.z,  ab[2]);
            aa[3] = fmaf(hka, w0.w,  aa[3]);  ab[3] = fmaf(hkb, w0.w,  ab[3]);
            aa[4] = fmaf(hka, w1v.x, aa[4]);  ab[4] = fmaf(hkb, w1v.x, ab[4]);
            aa[5] = fmaf(hka, w1v.y, aa[5]);  ab[5] = fmaf(hkb, w1v.y, ab[5]);
            aa[6] = fmaf(hka, w1v.z, aa[6]);  ab[6] = fmaf(hkb, w1v.z, ab[6]);
            aa[7] = fmaf(hka, w1v.w, aa[7]);  ab[7] = fmaf(hkb, w1v.w, ab[7]);
        }
#pragma unroll
        for (int m = 0; m < 8; m++) {
            int j = jc * 8 + m;
            const float4* W3P4 = (const float4*)(wsf + W3P_OFF + j * 8);
            float4 wa = W3P4[0];
            float  w4 = wsf[W3P_OFF + j * 8 + 4];
            float h2a = fast_tanh(aa[m]);
            float h2b = fast_tanh(ab[m]);
            lga[0] = fmaf(h2a, wa.x, lga[0]);  lgb[0] = fmaf(h2b, wa.x, lgb[0]);
            lga[1] = fmaf(h2a, wa.y, lga[1]);  lgb[1] = fmaf(h2b, wa.y, lgb[1]);
            lga[2] = fmaf(h2a, wa.z, lga[2]);  lgb[2] = fmaf(h2b, wa.z, lgb[2]);
            lga[3] = fmaf(h2a, wa.w, lga[3]);  lgb[3] = fmaf(h2b, wa.w, lgb[3]);
            lga[4] = fmaf(h2a, w4,   lga[4]);  lgb[4] = fmaf(h2b, w4,   lgb[4]);
        }
    }
    int ba = 0; float va = lga[0];
    int bb = 0; float vb = lgb[0];
#pragma unroll
    for (int c = 1; c < 5; c++) {
        if (lga[c] > va) { va = lga[c]; ba = c; }
        if (lgb[c] > vb) { vb = lgb[c]; bb = c; }
    }
    p0 = ba; p1 = bb;
}

// Dense sampler, 2 evals/thread; brackets written k-major into BND.
__global__ __launch_bounds__(256, 2) void sample_kernel(float* __restrict__ wsf,
                                                        int* __restrict__ cnt,
                                                        int* __restrict__ f0arr)
{
    __shared__ unsigned char smA[256], smB[256];
    const int b = blockIdx.x;                 // 0 .. 128*NSP-1
    const int n = b / NSP, sp = b - n * NSP;
    const int segA = 2 * sp, segB = 2 * sp + 1;
    const int t = threadIdx.x;
    const float rid = wsf[PERN_OFF + n * 8 + 4];

    int sA = segA * 255 + t; if (sA > MSAMP - 1) sA = MSAMP - 1;
    int sB = segB * 255 + t; if (sB > MSAMP - 1) sB = MSAMP - 1;
    int pA, pB;
    mlp_class2((float)sA * DU, (float)sB * DU, n, wsf, pA, pB);
    int mA = ((float)pA == rid) ? 1 : 0;
    int mB = ((float)pB == rid) ? 1 : 0;
    smA[t] = (unsigned char)mA;
    smB[t] = (unsigned char)mB;
    if (sp == 0 && t == 0) f0arr[n] = mA;
    __syncthreads();
    if (t < 255) {
        int s2 = segA * 255 + t;
        if (s2 + 1 <= MSAMP - 1 && smA[t] != smA[t + 1]) {
            int idx = atomicAdd(&cnt[n], 1);
            if (idx < MAXB) wsf[BND_OFF + idx * 128 + n] = (float)s2;
        }
        int s3 = segB * 255 + t;
        if (s3 + 1 <= MSAMP - 1 && smB[t] != smB[t + 1]) {
            int idx = atomicAdd(&cnt[n], 1);
            if (idx < MAXB) wsf[BND_OFF + idx * 128 + n] = (float)s3;
        }
    }
}

// Count pass: 2500 blocks x 16 points, coalesced k-major prologue (R21/R22)
// + software-pipelined loop (prefetch it+1's SLAT/CLAT/SDL — same addresses,
// bit-identical values; the ONLY change vs R22). No fence, no fused finalize
// (R23: the t0-fence path doubled WRITE_SIZE and collapsed busy to 28%).
__global__ __launch_bounds__(256, 2) void count_kernel(const float* __restrict__ wsf,
                                                       const int* __restrict__ f0arr,
                                                       unsigned* __restrict__ key)
{
    __shared__ int scnt[4][8];
    __shared__ unsigned skey[16];
    const int t = threadIdx.x;
    const int n = t & 127;
    const int h = t >> 7;
    const int w = t >> 6;

    float bs[MAXB];
#pragma unroll
    for (int k = 0; k < MAXB; k++) bs[k] = wsf[BND_OFF + k * 128 + n];
    const int f0 = f0arr[n];
    const float rid = wsf[PERN_OFF + n * 8 + 4];
    const float* pn = wsf + PERN_OFF + n * 8;
    const float slat2 = pn[0], clat2 = pn[1];
    const int base = blockIdx.x * 16 + h * 8;

    // prefetch iteration 0
    int gi0 = base / G, gj0 = base - gi0 * G;
    float s1n = wsf[SLAT_OFF + gi0], c1n = wsf[CLAT_OFF + gi0];
    float2 tvn = ((const float2*)(wsf + SDL_OFF))[gj0 * NPT + n];

#pragma unroll 1
    for (int it = 0; it < 8; ++it) {
        float s1 = s1n, c1 = c1n;
        float2 tv = tvn;
        if (it < 7) {                        // prefetch it+1 (overlaps body)
            int i1 = base + it + 1;
            int gi1 = i1 / G, gj1 = i1 - gi1 * G;
            s1n = wsf[SLAT_OFF + gi1];
            c1n = wsf[CLAT_OFF + gi1];
            tvn = ((const float2*)(wsf + SDL_OFF))[gj1 * NPT + n];
        }
        float sdl = tv.x, cdl = tv.y;
        float A = clat2 * sdl;
        float B = c1 * slat2 - s1 * clat2 * cdl;
        float numer = sqrtf(A * A + B * B);
        float denom = s1 * slat2 + c1 * clat2 * cdl;
        float u = (atan2f(numer, denom) * 6371.0f) / 100.0f;
        int c = 0, inside = 0;
#pragma unroll
        for (int k = 0; k < MAXB; k++) {
            float sk = bs[k];
            float lo = sk * DU;
            float hi = (sk + 1.0f) * DU;     // same exprs as sampler -> bit-identical
            c += (hi <= u) ? 1 : 0;
            inside |= (lo < u && u < hi) ? 1 : 0;
        }
        int m = f0 ^ (c & 1);
        if (inside) m = mlp_match(u, n, wsf, rid);   // exact, rare (noinline)
        unsigned long long bal = __ballot(m != 0);
        if ((t & 63) == 0) scnt[w][it] = __popcll(bal);
    }
    __syncthreads();
    if (t < 16) {
        int hh = t >> 3, j = t & 7;
        int i = blockIdx.x * 16 + hh * 8 + j;
        int num = scnt[hh * 2][j] + scnt[hh * 2 + 1][j];
        skey[t] = ((unsigned)num << 16) | (unsigned)(G2 - 1 - i);
    }
    __syncthreads();
    if (t == 0) {
        unsigned km = 0;
        for (int q = 0; q < 16; q++) km = max(km, skey[q]);
        atomicMax(key, km);
    }
}

// Finalize: exact MLP on winner row (1 block; inlined eval).
__global__ __launch_bounds__(NPT) void final_kernel(const float* __restrict__ wsf,
                                                    const unsigned* __restrict__ key,
                                                    float* __restrict__ out)
{
    unsigned k = *key;
    int i = (G2 - 1) - (int)(k & 0xFFFFu);
    int num = (int)(k >> 16);
    const int n = threadIdx.x;
    int gi = i / G, gj = i - gi * G;
    float s1 = wsf[SLAT_OFF + gi], c1 = wsf[CLAT_OFF + gi];
    const float* pn = wsf + PERN_OFF + n * 8;
    float slat2 = pn[0], clat2 = pn[1];
    float2 tv = ((const float2*)(wsf + SDL_OFF))[gj * NPT + n];
    float sdl = tv.x, cdl = tv.y;
    float A = clat2 * sdl;
    float B = c1 * slat2 - s1 * clat2 * cdl;
    float numer = sqrtf(A * A + B * B);
    float denom = s1 * slat2 + c1 * clat2 * cdl;
    float gd = atan2f(numer, denom) * 6371.0f;
    int pid = mlp_class_inl(gd / 100.0f, n, wsf);
    out[n] = (float)pid;
    float tim = pn[3];
    out[NPT + 2 * n + 0] = (gd / 100.0f) * 100.0f;
    out[NPT + 2 * n + 1] = (tim / 100.0f) * 100.0f;
    if (n == 0) {
        out[3 * NPT] = (float)num;
        out[3 * NPT + 1] = f_min_lon() + f_dlon() * (float)gj;
        out[3 * NPT + 2] = f_min_lat() + f_dlat() * (float)gi;
    }
}

// ================= R12 fallback path (ws too small) =================
template<bool TAB, bool PQ>
__device__ __forceinline__ void compute_pair2(int ia, int n,
                                              const float* __restrict__ wsf,
                                              int& pa, int& pb)
{
    const int ib = ia + 1;
    int gia = ia / G, gja = ia - gia * G;
    int gib = ib / G, gjb = ib - gib * G;
    float s1a, c1a, s1b, c1b;
    if (TAB) {
        s1a = wsf[SLAT_OFF + gia]; c1a = wsf[CLAT_OFF + gia];
        s1b = wsf[SLAT_OFF + gib]; c1b = wsf[CLAT_OFF + gib];
    } else {
        float lat1a = (f_min_lat() + f_dlat() * (float)gia) * f_rad();
        float lat1b = (f_min_lat() + f_dlat() * (float)gib) * f_rad();
        s1a = sinf(lat1a); c1a = cosf(lat1a);
        s1b = sinf(lat1b); c1b = cosf(lat1b);
    }
    const float* pn = wsf + PERN_OFF + n * 8;
    float slat2 = pn[0], clat2 = pn[1];
    float sdla, cdla, sdlb, cdlb;
    if (PQ) {
        const float2* T = (const float2*)(wsf + SDL_OFF);
        float2 ta = T[gja * NPT + n];
        float2 tb = T[gjb * NPT + n];
        sdla = ta.x; cdla = ta.y; sdlb = tb.x; cdlb = tb.y;
    } else {
        float lon2 = pn[2];
        float lon1a = (f_min_lon() + f_dlon() * (float)gja) * f_rad();
        float lon1b = (f_min_lon() + f_dlon() * (float)gjb) * f_rad();
        float dla = lon2 - lon1a, dlb = lon2 - lon1b;
        sdla = sinf(dla); cdla = cosf(dla);
        sdlb = sinf(dlb); cdlb = cosf(dlb);
    }
    float Aa = clat2 * sdla;
    float Ba = c1a * slat2 - s1a * clat2 * cdla;
    float Ab = clat2 * sdlb;
    float Bb = c1b * slat2 - s1b * clat2 * cdlb;
    float na_ = sqrtf(Aa * Aa + Ba * Ba);
    float nb_ = sqrtf(Ab * Ab + Bb * Bb);
    float da_ = s1a * slat2 + c1a * clat2 * cdla;
    float db_ = s1b * slat2 + c1b * clat2 * cdlb;
    float ua = (atan2f(na_, da_) * 6371.0f) / 100.0f;
    float ub = (atan2f(nb_, db_) * 6371.0f) / 100.0f;
    int pa_, pb_;
    mlp_class2(ua, ub, n, wsf, pa_, pb_);
    pa = pa_; pb = pb_;
}

template<bool TAB, bool PQ>
__global__ __launch_bounds__(256, 2) void fb_pass1(const float* __restrict__ wsf,
                                                   unsigned* __restrict__ key)
{
    __shared__ int sa[4], sb[4];
    const int t = threadIdx.x;
    const int n = t & 127;
    const int h = t >> 7;
    const int base = blockIdx.x * 4;
    const int ia = base + h * 2;
    int pa, pb;
    compute_pair2<TAB, PQ>(ia, n, wsf, pa, pb);
    float rid = wsf[PERN_OFF + n * 8 + 4];
    unsigned long long ba_ = __ballot((float)pa == rid);
    unsigned long long bb_ = __ballot((float)pb == rid);
    if ((t & 63) == 0) { sa[t >> 6] = __popcll(ba_); sb[t >> 6] = __popcll(bb_); }
    __syncthreads();
    if (t == 0) {
        int n0 = sa[0] + sa[1], n1 = sb[0] + sb[1];
        int n2 = sa[2] + sa[3], n3 = sb[2] + sb[3];
        unsigned k0 = ((unsigned)n0 << 16) | (unsigned)(G2 - 1 - (base + 0));
        unsigned k1 = ((unsigned)n1 << 16) | (unsigned)(G2 - 1 - (base + 1));
        unsigned k2 = ((unsigned)n2 << 16) | (unsigned)(G2 - 1 - (base + 2));
        unsigned k3 = ((unsigned)n3 << 16) | (unsigned)(G2 - 1 - (base + 3));
        atomicMax(key, max(max(k0, k1), max(k2, k3)));
    }
}

template<bool TAB, bool PQ>
__global__ __launch_bounds__(NPT) void fb_pass2(const float* __restrict__ wsf,
                                                const unsigned* __restrict__ key,
                                                float* __restrict__ out)
{
    unsigned k = *key;
    int i = (G2 - 1) - (int)(k & 0xFFFFu);
    int num = (int)(k >> 16);
    const int n = threadIdx.x;
    int gi = i / G, gj = i - gi * G;
    float s1, c1;
    if (TAB) { s1 = wsf[SLAT_OFF + gi]; c1 = wsf[CLAT_OFF + gi]; }
    else {
        float lat1 = (f_min_lat() + f_dlat() * (float)gi) * f_rad();
        s1 = sinf(lat1); c1 = cosf(lat1);
    }
    const float* pn = wsf + PERN_OFF + n * 8;
    float slat2 = pn[0], clat2 = pn[1];
    float sdl, cdl;
    if (PQ) {
        float2 tv = ((const float2*)(wsf + SDL_OFF))[gj * NPT + n];
        sdl = tv.x; cdl = tv.y;
    } else {
        float lon2 = pn[2];
        float lon1 = (f_min_lon() + f_dlon() * (float)gj) * f_rad();
        float dl = lon2 - lon1;
        sdl = sinf(dl); cdl = cosf(dl);
    }
    float A = clat2 * sdl;
    float B = c1 * slat2 - s1 * clat2 * cdl;
    float numer = sqrtf(A * A + B * B);
    float denom = s1 * slat2 + c1 * clat2 * cdl;
    float gd = atan2f(numer, denom) * 6371.0f;
    int pid = mlp_class_inl(gd / 100.0f, n, wsf);
    out[n] = (float)pid;
    float tim = pn[3];
    out[NPT + 2 * n + 0] = (gd / 100.0f) * 100.0f;
    out[NPT + 2 * n + 1] = (tim / 100.0f) * 100.0f;
    if (n == 0) {
        out[3 * NPT] = (float)num;
        out[3 * NPT + 1] = f_min_lon() + f_dlon() * (float)gj;
        out[3 * NPT + 2] = f_min_lat() + f_dlat() * (float)gi;
    }
}

extern "C" void kernel_launch(void* const* d_in, const int* in_sizes, int n_in,
                              void* d_out, int out_size, void* d_ws, size_t ws_size,
                              hipStream_t stream)
{
    const float* x   = (const float*)d_in[0];
    const float* w1  = (const float*)d_in[1];
    const float* b1  = (const float*)d_in[2];
    const float* g1  = (const float*)d_in[3];
    const float* be1 = (const float*)d_in[4];
    const float* m1  = (const float*)d_in[5];
    const float* v1  = (const float*)d_in[6];
    const float* w2  = (const float*)d_in[7];
    const float* b2  = (const float*)d_in[8];
    const float* g2  = (const float*)d_in[9];
    const float* be2 = (const float*)d_in[10];
    const float* m2  = (const float*)d_in[11];
    const float* v2  = (const float*)d_in[12];
    const float* w3  = (const float*)d_in[13];
    const float* b3  = (const float*)d_in[14];
    float* out = (float*)d_out;

    const size_t need_full = 1056 + 4ull * WS_TOTAL;
    if (ws_size >= need_full) {
        unsigned* hdr = (unsigned*)d_ws;
        unsigned* key = (unsigned*)d_ws;
        int* cnt = (int*)((char*)d_ws + 16);
        int* f0  = (int*)((char*)d_ws + 528);
        float* wsf = (float*)((char*)d_ws + 1056);
        setup_kernel<<<101, 256, 0, stream>>>(x, w1, b1, g1, be1, m1, v1,
                                              w2, b2, g2, be2, m2, v2, w3, b3,
                                              wsf, hdr, 1, 1);
        sample_kernel<<<128 * NSP, 256, 0, stream>>>(wsf, cnt, f0);
        count_kernel<<<G2 / 16, 256, 0, stream>>>(wsf, f0, key);
        final_kernel<<<1, NPT, 0, stream>>>(wsf, key, out);
        return;
    }

    // fallback: R12 path (wsf at d_ws+16)
    unsigned* key = (unsigned*)d_ws;
    float* wsf = (float*)((char*)d_ws + 16);
    const size_t need_tab = 16 + 4ull * (CLAT_OFF + 200);
    const size_t need_pq  = 16 + 4ull * (SDL_OFF + 200 * 128 * 2);
    const bool tab = ws_size >= need_tab;
    const bool pq  = ws_size >= need_pq;
    hipMemsetAsync(d_ws, 0, 16, stream);
    setup_kernel<<<pq ? 101 : 1, 256, 0, stream>>>(x, w1, b1, g1, be1, m1, v1,
                                                   w2, b2, g2, be2, m2, v2, w3, b3, wsf,
                                                   (unsigned*)nullptr,
                                                   tab ? 1 : 0, pq ? 1 : 0);
    if (pq) {
        fb_pass1<true, true><<<G2 / 4, 256, 0, stream>>>(wsf, key);
        fb_pass2<true, true><<<1, NPT, 0, stream>>>(wsf, key, out);
    } else if (tab) {
        fb_pass1<true, false><<<G2 / 4, 256, 0, stream>>>(wsf, key);
        fb_pass2<true, false><<<1, NPT, 0, stream>>>(wsf, key, out);
    } else {
        fb_pass1<false, false><<<G2 / 4, 256, 0, stream>>>(wsf, key);
        fb_pass2<false, false><<<1, NPT, 0, stream>>>(wsf, key, out);
    }
}